// Round 3
// baseline (139.426 us; speedup 1.0000x reference)
//
#include <hip/hip_runtime.h>
#include <hip/hip_bf16.h>

#define BATCH 16
#define INP   128
#define OUP   128
#define HH    56
#define WW    56
#define HID   768
#define KC    64
#define NCHUNK 12
#define TILE  14
#define HALO  16
#define NHPX  256
#define NIPX  196
#define NPPX  208
#define EPSV  1e-5f

typedef __attribute__((ext_vector_type(8))) short bf16x8;
typedef __attribute__((ext_vector_type(4))) float f32x4;

__device__ __forceinline__ unsigned short f2b(float f) {
    unsigned u = __float_as_uint(f);
    return (unsigned short)((u + 0x7FFFu + ((u >> 16) & 1u)) >> 16);   // RNE
}
__device__ __forceinline__ float blo(unsigned u){ return __uint_as_float(u << 16); }
__device__ __forceinline__ float bhi(unsigned u){ return __uint_as_float(u & 0xFFFF0000u); }
__device__ __forceinline__ unsigned pkbf(float lo, float hi) {
    unsigned r;
    asm("v_cvt_pk_bf16_f32 %0, %1, %2" : "=v"(r) : "v"(lo), "v"(hi));
    return r;
}

// ---------------- pre-kernel: fold BN into bf16 weights, once ----------------
__global__ void prep(const float* __restrict__ w1, const float* __restrict__ g1,
                     const float* __restrict__ b1, const float* __restrict__ m1, const float* __restrict__ v1,
                     const float* __restrict__ wdw, const float* __restrict__ g2,
                     const float* __restrict__ b2, const float* __restrict__ m2, const float* __restrict__ v2,
                     const float* __restrict__ w2, const float* __restrict__ g3,
                     const float* __restrict__ b3, const float* __restrict__ m3, const float* __restrict__ v3,
                     unsigned short* __restrict__ w1b, unsigned short* __restrict__ w2b,
                     float* __restrict__ be1o, float* __restrict__ wdsf,
                     float* __restrict__ be2o, float* __restrict__ be3o)
{
    int gid = blockIdx.x * blockDim.x + threadIdx.x;
    int stp = gridDim.x * blockDim.x;
    for (int i = gid; i < HID * INP; i += stp) {
        int r = i >> 7;
        float s = g1[r] * rsqrtf(v1[r] + EPSV);
        w1b[i] = f2b(w1[i] * s);
    }
    for (int i = gid; i < OUP * HID; i += stp) {
        int r = i / HID;
        float s = g3[r] * rsqrtf(v3[r] + EPSV);
        w2b[i] = f2b(w2[i] * s);
    }
    for (int i = gid; i < HID; i += stp) {
        float s1 = g1[i] * rsqrtf(v1[i] + EPSV);
        be1o[i] = b1[i] - m1[i] * s1;
        float s2 = g2[i] * rsqrtf(v2[i] + EPSV);
        be2o[i] = b2[i] - m2[i] * s2;
    }
    for (int i = gid; i < HID * 9; i += stp) {
        int c = i / 9;
        float s2 = g2[c] * rsqrtf(v2[c] + EPSV);
        wdsf[i] = wdw[i] * s2;
    }
    for (int i = gid; i < OUP; i += stp) {
        float s3 = g3[i] * rsqrtf(v3[i] + EPSV);
        be3o[i] = b3[i] - m3[i] * s3;
    }
}

// ---------------- fused main kernel ----------------
__launch_bounds__(512, 2)
__global__ void fused_ir(const float* __restrict__ x,
                         const unsigned short* __restrict__ w1b,
                         const unsigned short* __restrict__ w2b,
                         const float* __restrict__ be1g,
                         const float* __restrict__ wdsf,
                         const float* __restrict__ be2g,
                         const float* __restrict__ be3g,
                         const int* __restrict__ mask,
                         float* __restrict__ out)
{
    __shared__ unsigned short xs[NHPX * 128];     // 65536 B  bf16 x halo [px][c], slot-swizzled
    __shared__ unsigned short h1t[KC * 256];      // 32768 B  bf16 h1 [c][px], slot-swizzled
    __shared__ unsigned short h2s[NPPX * 64];     // 26624 B  bf16 h2 [px][c], slot-swizzled
    __shared__ float be1v[HID], be2v[HID];        // 6144 B
    __shared__ float be3v[OUP];                   // 512 B
    __shared__ float wds[KC * 9];                 // 2304 B
    __shared__ float mdv[NHPX];                   // 1024 B
    __shared__ float mfv_[NIPX];                  // 784 B
    __shared__ float mtmp[18 * 18];               // 1296 B

    const int t    = threadIdx.x;
    const int b    = blockIdx.y;
    const int tile = blockIdx.x;
    const int h0   = (tile >> 2) * TILE, w0 = (tile & 3) * TILE;
    const int lane = t & 63;
    const int wv   = t >> 6;        // wave 0..7
    const int g    = lane >> 4;     // k-octet
    const int r16  = lane & 15;

    // ---------------- prologue ----------------
    for (int i = t; i < HID; i += 512) { be1v[i] = be1g[i]; be2v[i] = be2g[i]; }
    if (t < OUP) be3v[t] = be3g[t];
    for (int i = t; i < 324; i += 512) {
        int iy = i / 18, ix = i - iy * 18;
        int gy = h0 + iy - 2, gx = w0 + ix - 2;
        float v = 0.f;
        if (gy >= 0 && gy < HH && gx >= 0 && gx < WW)
            v = (float)mask[(b * HH + gy) * WW + gx];
        mtmp[i] = v;
    }
    for (int i = t; i < (NPPX - NIPX) * 64; i += 512)     // zero h2s pad rows once
        h2s[NIPX * 64 + i] = 0;
    // stage x halo -> bf16 LDS (swizzled)
    for (int rep = 0; rep < 16; ++rep) {
        int id = t + rep * 512;
        int px = id & 255, c0 = (id >> 8) * 4;
        int hy = px >> 4, hx = px & 15;
        int gy = h0 + hy - 1, gx = w0 + hx - 1;
        ushort4 u; u.x = 0; u.y = 0; u.z = 0; u.w = 0;
        if (gy >= 0 && gy < HH && gx >= 0 && gx < WW) {
            const float* xp = x + (((size_t)b * INP + c0) * HH + gy) * WW + gx;
            u.x = f2b(xp[0]);
            u.y = f2b(xp[HH * WW]);
            u.z = f2b(xp[2 * HH * WW]);
            u.w = f2b(xp[3 * HH * WW]);
        }
        int el = px * 128 + (((c0 >> 3) ^ (px & 15)) << 3) + (c0 & 7);
        *(ushort4*)&xs[el] = u;
    }
    __syncthreads();
    for (int i = t; i < NHPX; i += 512) {
        int hy = i >> 4, hx = i & 15;
        int gy = h0 + hy - 1, gx = w0 + hx - 1;
        float mm = 0.f;
        #pragma unroll
        for (int dy = 0; dy < 3; ++dy)
            #pragma unroll
            for (int dx = 0; dx < 3; ++dx)
                mm = fmaxf(mm, mtmp[(hy + dy) * 18 + hx + dx]);
        if (gy < 0 || gy >= HH || gx < 0 || gx >= WW) mm = 0.f;
        mdv[i] = mm;
    }
    for (int i = t; i < NIPX; i += 512) {
        int iy = i / 14, ix = i - iy * 14;
        mfv_[i] = mtmp[(iy + 2) * 18 + ix + 2];
    }
    __syncthreads();

    f32x4 pacc[2][7];
    #pragma unroll
    for (int ot = 0; ot < 2; ++ot)
        #pragma unroll
        for (int j = 0; j < 7; ++j) {
            pacc[ot][j][0] = 0.f; pacc[ot][j][1] = 0.f;
            pacc[ot][j][2] = 0.f; pacc[ot][j][3] = 0.f;
        }

    const int nt0 = wv * 2;                              // E: this wave's 2 n-tiles
    const int otp = wv & 3, nh = wv >> 2, ntb = nh * 7;  // P: out-ch pair + n-half

    for (int ch = 0; ch < NCHUNK; ++ch) {
        const int k0 = ch * KC;
        // stage dw taps (BN2-scaled) for this chunk
        for (int i = t; i < KC * 9; i += 512) wds[i] = wdsf[k0 * 9 + i];

        // ---- phase E: expand MFMA, A=xs(px rows), B=w1b(ch cols) ----
        {
            bf16x8 wf[4][4];   // [ks][mt]
            #pragma unroll
            for (int ks = 0; ks < 4; ++ks)
                #pragma unroll
                for (int mt = 0; mt < 4; ++mt)
                    wf[ks][mt] = *(const bf16x8*)&w1b[(size_t)(k0 + mt * 16 + r16) * INP + ks * 32 + g * 8];
            f32x4 eacc[4][2];
            #pragma unroll
            for (int mt = 0; mt < 4; ++mt)
                #pragma unroll
                for (int n2 = 0; n2 < 2; ++n2) {
                    eacc[mt][n2][0] = 0.f; eacc[mt][n2][1] = 0.f;
                    eacc[mt][n2][2] = 0.f; eacc[mt][n2][3] = 0.f;
                }
            #pragma unroll
            for (int ks = 0; ks < 4; ++ks)
                #pragma unroll
                for (int n2 = 0; n2 < 2; ++n2) {
                    int px = (nt0 + n2) * 16 + r16;
                    bf16x8 af = *(const bf16x8*)&xs[px * 128 + (((ks * 4 + g) ^ (px & 15)) << 3)];
                    #pragma unroll
                    for (int mt = 0; mt < 4; ++mt)
                        eacc[mt][n2] = __builtin_amdgcn_mfma_f32_16x16x32_bf16(af, wf[ks][mt], eacc[mt][n2], 0, 0, 0);
                }
            // BN1(+fold) + relu6 + md, pack 4 px -> b64 write
            #pragma unroll
            for (int n2 = 0; n2 < 2; ++n2) {
                int px4 = (nt0 + n2) * 16 + g * 4;
                float4 md4 = *(const float4*)&mdv[px4];
                #pragma unroll
                for (int mt = 0; mt < 4; ++mt) {
                    float be = be1v[k0 + mt * 16 + r16];
                    float v0 = fminf(fmaxf(eacc[mt][n2][0] + be, 0.f), 6.f) * md4.x;
                    float v1 = fminf(fmaxf(eacc[mt][n2][1] + be, 0.f), 6.f) * md4.y;
                    float v2 = fminf(fmaxf(eacc[mt][n2][2] + be, 0.f), 6.f) * md4.z;
                    float v3 = fminf(fmaxf(eacc[mt][n2][3] + be, 0.f), 6.f) * md4.w;
                    uint2 pk; pk.x = pkbf(v0, v1); pk.y = pkbf(v2, v3);
                    int c = mt * 16 + r16;
                    int el = c * 256 + ((((px4 >> 3)) ^ (c & 15)) << 3) + (px4 & 7);
                    *(uint2*)&h1t[el] = pk;
                }
            }
        }
        __syncthreads();

        // ---- phase D: depthwise 3x3 + BN2(+fold) + relu6 + mf ----
        for (int rep = 0; rep < 2; ++rep) {
            int id = t + rep * 512;
            if (id < 896) {                       // 64 ch x 14 rows; y wave-uniform
                int c = id & 63, y = id >> 6;
                float rr[3][16];
                #pragma unroll
                for (int dy = 0; dy < 3; ++dy) {
                    int s0 = (y + dy) * 2;
                    uint4 q0 = *(const uint4*)&h1t[c * 256 + ((s0 ^ (c & 15)) << 3)];
                    uint4 q1 = *(const uint4*)&h1t[c * 256 + (((s0 + 1) ^ (c & 15)) << 3)];
                    rr[dy][0] = blo(q0.x);  rr[dy][1] = bhi(q0.x);
                    rr[dy][2] = blo(q0.y);  rr[dy][3] = bhi(q0.y);
                    rr[dy][4] = blo(q0.z);  rr[dy][5] = bhi(q0.z);
                    rr[dy][6] = blo(q0.w);  rr[dy][7] = bhi(q0.w);
                    rr[dy][8] = blo(q1.x);  rr[dy][9] = bhi(q1.x);
                    rr[dy][10] = blo(q1.y); rr[dy][11] = bhi(q1.y);
                    rr[dy][12] = blo(q1.z); rr[dy][13] = bhi(q1.z);
                    rr[dy][14] = blo(q1.w); rr[dy][15] = bhi(q1.w);
                }
                float wt[9];
                #pragma unroll
                for (int q = 0; q < 9; ++q) wt[q] = wds[c * 9 + q];
                float be = be2v[k0 + c];
                #pragma unroll
                for (int xx = 0; xx < 14; ++xx) {
                    float mv = mfv_[y * 14 + xx];   // wave-uniform
                    float v = 0.f;
                    if (mv != 0.f) {                // mv==1 here, skip the multiply
                        float s = rr[0][xx] * wt[0] + rr[0][xx + 1] * wt[1] + rr[0][xx + 2] * wt[2]
                                + rr[1][xx] * wt[3] + rr[1][xx + 1] * wt[4] + rr[1][xx + 2] * wt[5]
                                + rr[2][xx] * wt[6] + rr[2][xx + 1] * wt[7] + rr[2][xx + 2] * wt[8];
                        v = fminf(fmaxf(s + be, 0.f), 6.f);
                    }
                    int px = y * 14 + xx;
                    h2s[px * 64 + ((((c >> 3)) ^ (px & 7)) << 3) + (c & 7)] = f2b(v);
                }
            }
        }
        __syncthreads();

        // ---- phase P: project MFMA accumulate (A=w2b rows, B=h2s px cols) ----
        {
            bf16x8 pw[2][2];   // [ks][ot]
            #pragma unroll
            for (int ks = 0; ks < 2; ++ks)
                #pragma unroll
                for (int ot = 0; ot < 2; ++ot)
                    pw[ks][ot] = *(const bf16x8*)&w2b[(size_t)(otp * 32 + ot * 16 + r16) * HID + k0 + ks * 32 + g * 8];
            #pragma unroll
            for (int ks = 0; ks < 2; ++ks)
                #pragma unroll
                for (int j = 0; j < 7; ++j) {
                    int nt = ntb + j;
                    if (nt < 13) {
                        int px = nt * 16 + r16;
                        bf16x8 hb = *(const bf16x8*)&h2s[px * 64 + (((ks * 4 + g) ^ (px & 7)) << 3)];
                        #pragma unroll
                        for (int ot = 0; ot < 2; ++ot)
                            pacc[ot][j] = __builtin_amdgcn_mfma_f32_16x16x32_bf16(pw[ks][ot], hb, pacc[ot][j], 0, 0, 0);
                    }
                }
        }
        // no trailing barrier: next E writes h1t (D done reading pre-barrier), P reads h2s only
    }

    // ---------------- epilogue: out = x + (proj + be3) * mf ----------------
    #pragma unroll
    for (int ot = 0; ot < 2; ++ot) {
        int ob = otp * 32 + ot * 16 + g * 4;
        float4 be4 = *(const float4*)&be3v[ob];
        #pragma unroll
        for (int j = 0; j < 7; ++j) {
            int nt = ntb + j;
            int px = nt * 16 + r16;
            if (nt < 13 && px < NIPX) {
                int iy = px / 14, ix = px - iy * 14;
                int gy = h0 + iy, gx = w0 + ix;
                float mv = mfv_[px];
                size_t base = (((size_t)b * OUP + ob) * HH + gy) * WW + gx;
                out[base]                = x[base]                + (pacc[ot][j][0] + be4.x) * mv;
                out[base + HH * WW]      = x[base + HH * WW]      + (pacc[ot][j][1] + be4.y) * mv;
                out[base + 2 * HH * WW]  = x[base + 2 * HH * WW]  + (pacc[ot][j][2] + be4.z) * mv;
                out[base + 3 * HH * WW]  = x[base + 3 * HH * WW]  + (pacc[ot][j][3] + be4.w) * mv;
            }
        }
    }
}

extern "C" void kernel_launch(void* const* d_in, const int* in_sizes, int n_in,
                              void* d_out, int out_size, void* d_ws, size_t ws_size,
                              hipStream_t stream) {
    (void)in_sizes; (void)n_in; (void)out_size; (void)ws_size;
    const float* x   = (const float*)d_in[0];
    const float* w1  = (const float*)d_in[1];
    const float* g1  = (const float*)d_in[2];
    const float* b1  = (const float*)d_in[3];
    const float* m1  = (const float*)d_in[4];
    const float* v1  = (const float*)d_in[5];
    const float* wdw = (const float*)d_in[6];
    const float* g2  = (const float*)d_in[7];
    const float* b2  = (const float*)d_in[8];
    const float* m2  = (const float*)d_in[9];
    const float* v2  = (const float*)d_in[10];
    const float* w2  = (const float*)d_in[11];
    const float* g3  = (const float*)d_in[12];
    const float* b3  = (const float*)d_in[13];
    const float* m3  = (const float*)d_in[14];
    const float* v3  = (const float*)d_in[15];
    const int*  mask = (const int*)d_in[16];
    float* out = (float*)d_out;

    char* ws = (char*)d_ws;                       // 427,520 B used
    unsigned short* w1b = (unsigned short*)ws;                 // 196608
    unsigned short* w2b = (unsigned short*)(ws + 196608);      // 196608
    float* be1o = (float*)(ws + 393216);                       // 3072
    float* wdsf = (float*)(ws + 396288);                       // 27648
    float* be2o = (float*)(ws + 423936);                       // 3072
    float* be3o = (float*)(ws + 427008);                       // 512

    prep<<<128, 256, 0, stream>>>(w1, g1, b1, m1, v1, wdw, g2, b2, m2, v2,
                                  w2, g3, b3, m3, v3, w1b, w2b, be1o, wdsf, be2o, be3o);
    fused_ir<<<dim3(16, BATCH), 512, 0, stream>>>(x, w1b, w2b, be1o, wdsf, be2o, be3o, mask, out);
}

// Round 4
// 136.145 us; speedup vs baseline: 1.0241x; 1.0241x over previous
//
#include <hip/hip_runtime.h>
#include <hip/hip_bf16.h>

#define BATCH 16
#define INP   128
#define OUP   128
#define HH    56
#define WW    56
#define HID   768
#define KC    64
#define NCHUNK 12
#define TILE  14
#define HALO  16
#define NHPX  256
#define NIPX  196
#define NPPX  208
#define EPSV  1e-5f

typedef __attribute__((ext_vector_type(8))) short bf16x8;
typedef __attribute__((ext_vector_type(4))) float f32x4;

__device__ __forceinline__ unsigned short f2b(float f) {
    unsigned u = __float_as_uint(f);
    return (unsigned short)((u + 0x7FFFu + ((u >> 16) & 1u)) >> 16);   // RNE
}
__device__ __forceinline__ float blo(unsigned u){ return __uint_as_float(u << 16); }
__device__ __forceinline__ float bhi(unsigned u){ return __uint_as_float(u & 0xFFFF0000u); }
__device__ __forceinline__ unsigned pkbf(float lo, float hi) {
    unsigned r;
    asm("v_cvt_pk_bf16_f32 %0, %1, %2" : "=v"(r) : "v"(lo), "v"(hi));
    return r;
}

// ---------------- pre-kernel: fold BN into bf16 weights, once ----------------
__global__ void prep(const float* __restrict__ w1, const float* __restrict__ g1,
                     const float* __restrict__ b1, const float* __restrict__ m1, const float* __restrict__ v1,
                     const float* __restrict__ wdw, const float* __restrict__ g2,
                     const float* __restrict__ b2, const float* __restrict__ m2, const float* __restrict__ v2,
                     const float* __restrict__ w2, const float* __restrict__ g3,
                     const float* __restrict__ b3, const float* __restrict__ m3, const float* __restrict__ v3,
                     unsigned short* __restrict__ w1b, unsigned short* __restrict__ w2b,
                     float* __restrict__ be1o, float* __restrict__ wdsf,
                     float* __restrict__ be2o, float* __restrict__ be3o)
{
    int gid = blockIdx.x * blockDim.x + threadIdx.x;
    int stp = gridDim.x * blockDim.x;
    for (int i = gid; i < HID * INP; i += stp) {
        int r = i >> 7;
        float s = g1[r] * rsqrtf(v1[r] + EPSV);
        w1b[i] = f2b(w1[i] * s);
    }
    for (int i = gid; i < OUP * HID; i += stp) {
        int r = i / HID;
        float s = g3[r] * rsqrtf(v3[r] + EPSV);
        w2b[i] = f2b(w2[i] * s);
    }
    for (int i = gid; i < HID; i += stp) {
        float s1 = g1[i] * rsqrtf(v1[i] + EPSV);
        be1o[i] = b1[i] - m1[i] * s1;
        float s2 = g2[i] * rsqrtf(v2[i] + EPSV);
        be2o[i] = b2[i] - m2[i] * s2;
    }
    for (int i = gid; i < HID * 9; i += stp) {
        int c = i / 9;
        float s2 = g2[c] * rsqrtf(v2[c] + EPSV);
        wdsf[i] = wdw[i] * s2;
    }
    for (int i = gid; i < OUP; i += stp) {
        float s3 = g3[i] * rsqrtf(v3[i] + EPSV);
        be3o[i] = b3[i] - m3[i] * s3;
    }
}

// ---------------- fused main kernel (software-pipelined E/D/P) ----------------
__launch_bounds__(512, 2)
__global__ void fused_ir(const float* __restrict__ x,
                         const unsigned short* __restrict__ w1b,
                         const unsigned short* __restrict__ w2b,
                         const float* __restrict__ be1g,
                         const float* __restrict__ wdsf,
                         const float* __restrict__ be2g,
                         const float* __restrict__ be3g,
                         const int* __restrict__ mask,
                         float* __restrict__ out)
{
    __shared__ unsigned short h1t[2][KC * 256];   // 64 KB; overlaid as xs[256*128] in prologue
    __shared__ unsigned short h2s[2][NPPX * 64];  // 52 KB
    __shared__ float be1v[HID], be2v[HID];        // 6 KB
    __shared__ float be3v[OUP];                   // 0.5 KB
    __shared__ float wdsb[2][KC * 9];             // 4.6 KB
    __shared__ float mdv[NHPX];                   // 1 KB
    __shared__ float mfv_[NIPX];                  // 0.8 KB
    __shared__ float mtmp[18 * 18];               // 1.3 KB

    const int t    = threadIdx.x;
    const int b    = blockIdx.y;
    const int tile = blockIdx.x;
    const int h0   = (tile >> 2) * TILE, w0 = (tile & 3) * TILE;
    const int lane = t & 63;
    const int wv   = t >> 6;
    const int g    = lane >> 4;
    const int r16  = lane & 15;

    unsigned short* xs = &h1t[0][0];    // prologue-only overlay (64 KB = 256 px * 128 ch)

    // ---------------- prologue ----------------
    for (int i = t; i < HID; i += 512) { be1v[i] = be1g[i]; be2v[i] = be2g[i]; }
    if (t < OUP) be3v[t] = be3g[t];
    for (int i = t; i < 324; i += 512) {
        int iy = i / 18, ix = i - iy * 18;
        int gy = h0 + iy - 2, gx = w0 + ix - 2;
        float v = 0.f;
        if (gy >= 0 && gy < HH && gx >= 0 && gx < WW)
            v = (float)mask[(b * HH + gy) * WW + gx];
        mtmp[i] = v;
    }
    for (int q = t; q < (NPPX - NIPX) * 64; q += 512) {   // zero pad rows of BOTH h2s buffers
        h2s[0][NIPX * 64 + q] = 0;
        h2s[1][NIPX * 64 + q] = 0;
    }
    // stage x halo -> bf16 xs (swizzled [px][c])
    for (int rep = 0; rep < 16; ++rep) {
        int id = t + rep * 512;
        int px = id & 255, c0 = (id >> 8) * 4;
        int hy = px >> 4, hx = px & 15;
        int gy = h0 + hy - 1, gx = w0 + hx - 1;
        ushort4 u; u.x = 0; u.y = 0; u.z = 0; u.w = 0;
        if (gy >= 0 && gy < HH && gx >= 0 && gx < WW) {
            const float* xp = x + (((size_t)b * INP + c0) * HH + gy) * WW + gx;
            u.x = f2b(xp[0]);
            u.y = f2b(xp[HH * WW]);
            u.z = f2b(xp[2 * HH * WW]);
            u.w = f2b(xp[3 * HH * WW]);
        }
        int el = px * 128 + (((c0 >> 3) ^ (px & 15)) << 3) + (c0 & 7);
        *(ushort4*)&xs[el] = u;
    }
    __syncthreads();
    for (int i = t; i < NHPX; i += 512) {
        int hy = i >> 4, hx = i & 15;
        int gy = h0 + hy - 1, gx = w0 + hx - 1;
        float mm = 0.f;
        #pragma unroll
        for (int dy = 0; dy < 3; ++dy)
            #pragma unroll
            for (int dx = 0; dx < 3; ++dx)
                mm = fmaxf(mm, mtmp[(hy + dy) * 18 + hx + dx]);
        if (gy < 0 || gy >= HH || gx < 0 || gx >= WW) mm = 0.f;
        mdv[i] = mm;
    }
    for (int i = t; i < NIPX; i += 512) {
        int iy = i / 14, ix = i - iy * 14;
        mfv_[i] = mtmp[(iy + 2) * 18 + ix + 2];
    }
    // x A-fragments -> registers (reused by all 12 chunks; E reads no LDS after this)
    const int nt0 = wv * 2;
    bf16x8 xfrag[2][4];
    #pragma unroll
    for (int n2 = 0; n2 < 2; ++n2) {
        int px = (nt0 + n2) * 16 + r16;
        #pragma unroll
        for (int ks = 0; ks < 4; ++ks)
            xfrag[n2][ks] = *(const bf16x8*)&xs[px * 128 + (((ks * 4 + g) ^ (px & 15)) << 3)];
    }
    __syncthreads();     // xs dead; h1t buffers live from here

    f32x4 pacc[2][7];
    #pragma unroll
    for (int ot = 0; ot < 2; ++ot)
        #pragma unroll
        for (int j = 0; j < 7; ++j) {
            pacc[ot][j][0] = 0.f; pacc[ot][j][1] = 0.f;
            pacc[ot][j][2] = 0.f; pacc[ot][j][3] = 0.f;
        }

    const int otp = wv & 3, ntb = (wv >> 2) * 7;

    // ---- phase lambdas ----
    auto stageWds = [&](int ch) {
        for (int q = t; q < KC * 9; q += 512)
            wdsb[ch & 1][q] = wdsf[ch * (KC * 9) + q];
    };

    auto phaseE = [&](int ch) {
        const int k0 = ch * KC;
        unsigned short* h1w = h1t[ch & 1];
        f32x4 eacc[4][2];
        #pragma unroll
        for (int mt = 0; mt < 4; ++mt)
            #pragma unroll
            for (int n2 = 0; n2 < 2; ++n2) {
                eacc[mt][n2][0] = 0.f; eacc[mt][n2][1] = 0.f;
                eacc[mt][n2][2] = 0.f; eacc[mt][n2][3] = 0.f;
            }
        bf16x8 wreg[2][4];
        #pragma unroll
        for (int mt = 0; mt < 4; ++mt)
            wreg[0][mt] = *(const bf16x8*)&w1b[(size_t)(k0 + mt * 16 + r16) * INP + g * 8];
        #pragma unroll
        for (int ks = 0; ks < 4; ++ks) {
            if (ks < 3) {
                #pragma unroll
                for (int mt = 0; mt < 4; ++mt)
                    wreg[(ks + 1) & 1][mt] = *(const bf16x8*)&w1b[(size_t)(k0 + mt * 16 + r16) * INP + (ks + 1) * 32 + g * 8];
            }
            #pragma unroll
            for (int n2 = 0; n2 < 2; ++n2)
                #pragma unroll
                for (int mt = 0; mt < 4; ++mt)
                    eacc[mt][n2] = __builtin_amdgcn_mfma_f32_16x16x32_bf16(xfrag[n2][ks], wreg[ks & 1][mt], eacc[mt][n2], 0, 0, 0);
        }
        #pragma unroll
        for (int n2 = 0; n2 < 2; ++n2) {
            const int px4 = (nt0 + n2) * 16 + g * 4;
            const float4 md4 = *(const float4*)&mdv[px4];
            const int sl = (nt0 + n2) * 2 + (g >> 1);
            #pragma unroll
            for (int mt = 0; mt < 4; ++mt) {
                const int c = mt * 16 + r16;
                const float be = be1v[k0 + c];
                float v0 = fminf(fmaxf(eacc[mt][n2][0] + be, 0.f), 6.f) * md4.x;
                float v1 = fminf(fmaxf(eacc[mt][n2][1] + be, 0.f), 6.f) * md4.y;
                float v2 = fminf(fmaxf(eacc[mt][n2][2] + be, 0.f), 6.f) * md4.z;
                float v3 = fminf(fmaxf(eacc[mt][n2][3] + be, 0.f), 6.f) * md4.w;
                uint2 pk; pk.x = pkbf(v0, v1); pk.y = pkbf(v2, v3);
                *(uint2*)&h1w[c * 256 + (((sl) ^ (c & 31)) << 3) + ((g & 1) << 2)] = pk;
            }
        }
    };

    auto phaseD = [&](int ch) {
        const int k0 = ch * KC;
        const unsigned short* h1r = h1t[ch & 1];
        unsigned short* h2w = h2s[ch & 1];
        const float* wdl = wdsb[ch & 1];
        #pragma unroll
        for (int rep = 0; rep < 2; ++rep) {
            const int id = t + rep * 512;
            if (id < 896) {
                const int c = id & 63, y = id >> 6;
                float rr[3][16];
                #pragma unroll
                for (int dy = 0; dy < 3; ++dy) {
                    const int s0 = (y + dy) * 2;
                    const uint4 q0 = *(const uint4*)&h1r[c * 256 + ((s0 ^ (c & 31)) << 3)];
                    const uint4 q1 = *(const uint4*)&h1r[c * 256 + (((s0 + 1) ^ (c & 31)) << 3)];
                    rr[dy][0] = blo(q0.x);  rr[dy][1] = bhi(q0.x);
                    rr[dy][2] = blo(q0.y);  rr[dy][3] = bhi(q0.y);
                    rr[dy][4] = blo(q0.z);  rr[dy][5] = bhi(q0.z);
                    rr[dy][6] = blo(q0.w);  rr[dy][7] = bhi(q0.w);
                    rr[dy][8] = blo(q1.x);  rr[dy][9] = bhi(q1.x);
                    rr[dy][10] = blo(q1.y); rr[dy][11] = bhi(q1.y);
                    rr[dy][12] = blo(q1.z); rr[dy][13] = bhi(q1.z);
                    rr[dy][14] = blo(q1.w); rr[dy][15] = bhi(q1.w);
                }
                float wt[9];
                #pragma unroll
                for (int q = 0; q < 9; ++q) wt[q] = wdl[c * 9 + q];
                const float be = be2v[k0 + c];
                #pragma unroll
                for (int xx = 0; xx < 14; ++xx) {
                    const float mv = mfv_[y * 14 + xx];   // wave-uniform
                    float v = 0.f;
                    if (mv != 0.f) {
                        float s = rr[0][xx] * wt[0] + rr[0][xx + 1] * wt[1] + rr[0][xx + 2] * wt[2]
                                + rr[1][xx] * wt[3] + rr[1][xx + 1] * wt[4] + rr[1][xx + 2] * wt[5]
                                + rr[2][xx] * wt[6] + rr[2][xx + 1] * wt[7] + rr[2][xx + 2] * wt[8];
                        v = fminf(fmaxf(s + be, 0.f), 6.f);
                    }
                    const int px = y * 14 + xx;
                    h2w[px * 64 + ((((c >> 3) ^ (px & 7))) << 3) + (c & 7)] = f2b(v);
                }
            }
        }
    };

    auto phaseP = [&](int ch) {
        const int k0 = ch * KC;
        const unsigned short* h2r = h2s[ch & 1];
        bf16x8 pw[2][2];
        #pragma unroll
        for (int ks = 0; ks < 2; ++ks)
            #pragma unroll
            for (int ot = 0; ot < 2; ++ot)
                pw[ks][ot] = *(const bf16x8*)&w2b[(size_t)(otp * 32 + ot * 16 + r16) * HID + k0 + ks * 32 + g * 8];
        #pragma unroll
        for (int ks = 0; ks < 2; ++ks)
            #pragma unroll
            for (int j = 0; j < 7; ++j) {
                const int nt = ntb + j;
                if (nt < 13) {
                    const int px = nt * 16 + r16;
                    const bf16x8 hb = *(const bf16x8*)&h2r[px * 64 + ((((ks * 4 + g) ^ (px & 7))) << 3)];
                    #pragma unroll
                    for (int ot = 0; ot < 2; ++ot)
                        pacc[ot][j] = __builtin_amdgcn_mfma_f32_16x16x32_bf16(pw[ks][ot], hb, pacc[ot][j], 0, 0, 0);
                }
            }
    };

    // ---- pipelined schedule: iter i runs E(i) | D(i-1) | P(i-2), one barrier each ----
    stageWds(0); phaseE(0);
    __syncthreads();
    stageWds(1); phaseD(0); phaseE(1);
    __syncthreads();
    #pragma unroll 1
    for (int i = 2; i < NCHUNK; ++i) {
        stageWds(i);
        phaseD(i - 1);
        phaseP(i - 2);
        phaseE(i);
        __syncthreads();
    }
    phaseD(NCHUNK - 1);
    phaseP(NCHUNK - 2);
    __syncthreads();
    phaseP(NCHUNK - 1);

    // ---------------- epilogue: out = x + (proj + be3) * mf ----------------
    #pragma unroll
    for (int ot = 0; ot < 2; ++ot) {
        const int ob = otp * 32 + ot * 16 + g * 4;
        const float4 be4 = *(const float4*)&be3v[ob];
        #pragma unroll
        for (int j = 0; j < 7; ++j) {
            const int nt = ntb + j;
            const int px = nt * 16 + r16;
            if (nt < 13 && px < NIPX) {
                const int iy = px / 14, ix = px - iy * 14;
                const int gy = h0 + iy, gx = w0 + ix;
                const float mv = mfv_[px];
                const size_t base = (((size_t)b * OUP + ob) * HH + gy) * WW + gx;
                out[base]               = x[base]               + (pacc[ot][j][0] + be4.x) * mv;
                out[base + HH * WW]     = x[base + HH * WW]     + (pacc[ot][j][1] + be4.y) * mv;
                out[base + 2 * HH * WW] = x[base + 2 * HH * WW] + (pacc[ot][j][2] + be4.z) * mv;
                out[base + 3 * HH * WW] = x[base + 3 * HH * WW] + (pacc[ot][j][3] + be4.w) * mv;
            }
        }
    }
}

extern "C" void kernel_launch(void* const* d_in, const int* in_sizes, int n_in,
                              void* d_out, int out_size, void* d_ws, size_t ws_size,
                              hipStream_t stream) {
    (void)in_sizes; (void)n_in; (void)out_size; (void)ws_size;
    const float* x   = (const float*)d_in[0];
    const float* w1  = (const float*)d_in[1];
    const float* g1  = (const float*)d_in[2];
    const float* b1  = (const float*)d_in[3];
    const float* m1  = (const float*)d_in[4];
    const float* v1  = (const float*)d_in[5];
    const float* wdw = (const float*)d_in[6];
    const float* g2  = (const float*)d_in[7];
    const float* b2  = (const float*)d_in[8];
    const float* m2  = (const float*)d_in[9];
    const float* v2  = (const float*)d_in[10];
    const float* w2  = (const float*)d_in[11];
    const float* g3  = (const float*)d_in[12];
    const float* b3  = (const float*)d_in[13];
    const float* m3  = (const float*)d_in[14];
    const float* v3  = (const float*)d_in[15];
    const int*  mask = (const int*)d_in[16];
    float* out = (float*)d_out;

    char* ws = (char*)d_ws;
    unsigned short* w1b = (unsigned short*)ws;                 // 196608 B
    unsigned short* w2b = (unsigned short*)(ws + 196608);      // 196608 B
    float* be1o = (float*)(ws + 393216);                       // 3072 B
    float* wdsf = (float*)(ws + 396288);                       // 27648 B
    float* be2o = (float*)(ws + 423936);                       // 3072 B
    float* be3o = (float*)(ws + 427008);                       // 512 B

    prep<<<128, 256, 0, stream>>>(w1, g1, b1, m1, v1, wdw, g2, b2, m2, v2,
                                  w2, g3, b3, m3, v3, w1b, w2b, be1o, wdsf, be2o, be3o);
    fused_ir<<<dim3(16, BATCH), 512, 0, stream>>>(x, w1b, w2b, be1o, wdsf, be2o, be3o, mask, out);
}